// Round 8
// baseline (514.178 us; speedup 1.0000x reference)
//
#include <hip/hip_runtime.h>
#include <hip/hip_bf16.h>
#include <math.h>

typedef __attribute__((ext_vector_type(8))) short bh8;
typedef __attribute__((ext_vector_type(4))) short sh4;
typedef __attribute__((ext_vector_type(4))) float fx4;

__device__ __forceinline__ fx4 mfma_bf16(bh8 a, bh8 b, fx4 c) {
    return __builtin_amdgcn_mfma_f32_16x16x32_bf16(a, b, c, 0, 0, 0);
}

// async global->LDS, 16B per lane. LDS dest = wave-uniform base + lane*16.
__device__ __forceinline__ void gload16(const __hip_bfloat16* g, __hip_bfloat16* l) {
    __builtin_amdgcn_global_load_lds(
        (const __attribute__((address_space(1))) void*)g,
        (__attribute__((address_space(3))) void*)l,
        16, 0, 0);
}

// branchless erf, Abramowitz-Stegun 7.1.26, |abs err| <= 1.5e-7 (<< bf16 rounding).
__device__ __forceinline__ float fast_erf(float u) {
    float au = fabsf(u);
    float t  = __builtin_amdgcn_rcpf(1.0f + 0.3275911f * au);
    float p  = ((((1.061405429f * t - 1.453152027f) * t + 1.421413741f) * t
                 - 0.284496736f) * t + 0.254829592f) * t;
    float e  = __expf(-u * u);
    return copysignf(1.0f - p * e, u);
}

// lgkm fence for wave-private LDS write->read handoff (rule #18: sched_barrier
// after inline-asm waitcnt so MFMA isn't hoisted past it).
#define LGKM0  do { asm volatile("s_waitcnt lgkmcnt(0)" ::: "memory"); \
                    __builtin_amdgcn_sched_barrier(0); } while (0)

// ---------------- weight convert+transpose: W[K][N] fp32 -> Wt[N][K] bf16 ----------------
__global__ __launch_bounds__(256)
void convw_k(const float* __restrict__ W, __hip_bfloat16* __restrict__ Wt, int K, int Nn)
{
    int idx = blockIdx.x * 256 + threadIdx.x;
    if (idx < K * Nn) {
        int k = idx / Nn, n = idx - k * Nn;
        Wt[(size_t)n * K + k] = __float2bfloat16(W[idx]);
    }
}

// ---------------- LN1 + shift + window-partition gather -> xw bf16 (window order) -------
__global__ __launch_bounds__(256)
void ln1_gather_k(const float* __restrict__ x, const float* __restrict__ g,
                  const float* __restrict__ bia, __hip_bfloat16* __restrict__ xw)
{
    const int wave = threadIdx.x >> 6, lane = threadIdx.x & 63;
    const int t = blockIdx.x * 4 + wave;        // window-ordered token, < 100352
    const int w = t / 49, n = t - w * 49;
    const int b = w >> 6, wrem = w & 63, wi = wrem >> 3, wj = wrem & 7;
    const int i = n / 7, j = n - i * 7;
    int sr = wi * 7 + i + 3; if (sr >= 56) sr -= 56;
    int sc = wj * 7 + j + 3; if (sc >= 56) sc -= 56;
    const float* xp = x + ((size_t)b * 3136 + sr * 56 + sc) * 192;
    float v0 = xp[lane], v1 = xp[lane + 64], v2 = xp[lane + 128];
    float s = v0 + v1 + v2;
    float q = v0 * v0 + v1 * v1 + v2 * v2;
    for (int off = 32; off > 0; off >>= 1) {
        s += __shfl_down(s, off, 64);
        q += __shfl_down(q, off, 64);
    }
    s = __shfl(s, 0, 64); q = __shfl(q, 0, 64);
    float mean = s * (1.0f / 192.0f);
    float var  = q * (1.0f / 192.0f) - mean * mean;
    float rstd = rsqrtf(var + 1e-5f);
    __hip_bfloat16* op = xw + (size_t)t * 192;
    op[lane]       = __float2bfloat16((v0 - mean) * rstd * g[lane]       + bia[lane]);
    op[lane + 64]  = __float2bfloat16((v1 - mean) * rstd * g[lane + 64]  + bia[lane + 64]);
    op[lane + 128] = __float2bfloat16((v2 - mean) * rstd * g[lane + 128] + bia[lane + 128]);
}

// ---------------- GEMM v2: 128x64 tile, global_load_lds staging ----------------
// C[M][NOUT] = A[M][K] * Bt[NOUT][K]^T + epilogue
// MODE 0: qkv (+bias, scale first 192 cols, out bf16)
template<int MODE, int K, int NOUT>
__global__ __launch_bounds__(256)
void gemm2_k(const __hip_bfloat16* __restrict__ A,
             const __hip_bfloat16* __restrict__ Bt,
             const float* __restrict__ bias,
             const float* __restrict__ resid,
             void* __restrict__ outv)
{
    __shared__ __align__(16) __hip_bfloat16 As[128 * 32];   // 8 KB
    __shared__ __align__(16) __hip_bfloat16 Bs[64 * 32];    // 4 KB
    const int tid  = threadIdx.x;
    const int lane = tid & 63, wave = tid >> 6;
    const int quad = lane >> 4, l15 = lane & 15;
    const int m0 = blockIdx.x * 128, n0 = blockIdx.y * 64;

    const int arow = lane >> 2, acol = (lane & 3) * 8;
    const __hip_bfloat16* Ag0 = A  + (size_t)(m0 + wave * 32 + arow)      * K + acol;
    const __hip_bfloat16* Ag1 = A  + (size_t)(m0 + wave * 32 + 16 + arow) * K + acol;
    const __hip_bfloat16* Bg  = Bt + (size_t)(n0 + wave * 16 + arow)      * K + acol;
    __hip_bfloat16* Al0 = &As[(wave * 32)      * 32];
    __hip_bfloat16* Al1 = &As[(wave * 32 + 16) * 32];
    __hip_bfloat16* Bl  = &Bs[(wave * 16)      * 32];

    fx4 acc[2][4];
#pragma unroll
    for (int mi = 0; mi < 2; mi++)
#pragma unroll
        for (int ni = 0; ni < 4; ni++) acc[mi][ni] = {0.f, 0.f, 0.f, 0.f};

    for (int k0 = 0; k0 < K; k0 += 32) {
        gload16(Ag0 + k0, Al0);
        gload16(Ag1 + k0, Al1);
        gload16(Bg  + k0, Bl);
        __syncthreads();
        bh8 a0 = *(const bh8*)&As[(wave * 32 + l15)      * 32 + quad * 8];
        bh8 a1 = *(const bh8*)&As[(wave * 32 + 16 + l15) * 32 + quad * 8];
        bh8 b0 = *(const bh8*)&Bs[(0 * 16 + l15) * 32 + quad * 8];
        bh8 b1 = *(const bh8*)&Bs[(1 * 16 + l15) * 32 + quad * 8];
        bh8 b2 = *(const bh8*)&Bs[(2 * 16 + l15) * 32 + quad * 8];
        bh8 b3 = *(const bh8*)&Bs[(3 * 16 + l15) * 32 + quad * 8];
        acc[0][0] = mfma_bf16(a0, b0, acc[0][0]);
        acc[0][1] = mfma_bf16(a0, b1, acc[0][1]);
        acc[0][2] = mfma_bf16(a0, b2, acc[0][2]);
        acc[0][3] = mfma_bf16(a0, b3, acc[0][3]);
        acc[1][0] = mfma_bf16(a1, b0, acc[1][0]);
        acc[1][1] = mfma_bf16(a1, b1, acc[1][1]);
        acc[1][2] = mfma_bf16(a1, b2, acc[1][2]);
        acc[1][3] = mfma_bf16(a1, b3, acc[1][3]);
        __syncthreads();
    }

#pragma unroll
    for (int mi = 0; mi < 2; mi++)
#pragma unroll
    for (int ni = 0; ni < 4; ni++) {
        const int n = n0 + ni * 16 + l15;
        const float bn = bias[n];
#pragma unroll
        for (int r = 0; r < 4; r++) {
            const int m = m0 + wave * 32 + mi * 16 + quad * 4 + r;
            float v = acc[mi][ni][r] + bn;
            if (MODE == 0) {
                if (n < 192) v *= 0.17677669529663687f;   // SCALE = 32^-0.5 on q
                ((__hip_bfloat16*)outv)[(size_t)m * NOUT + n] = __float2bfloat16(v);
            } else if (MODE == 2) {
                v = 0.5f * v * (1.0f + erff(v * 0.70710678118654752f));
                ((__hip_bfloat16*)outv)[(size_t)m * NOUT + n] = __float2bfloat16(v);
            } else {
                ((float*)outv)[(size_t)m * NOUT + n] = v + resid[(size_t)m * NOUT + n];
            }
        }
    }
}

// ---------------- fused MLP v7: small-tile high-occupancy ----------------
// DIAGNOSIS (R4==R7 at 152us): occupancy was REGISTER-capped, not LDS/barrier-
// capped. acc2[2][12]=96 AGPR + 108 VGPR ~= 204 regs/thread -> 2 waves/SIMD
// in every variant since R4 (gfx950 unified VGPR/AGPR file).
// FIX: 16 rows/wave -> acc2[12]=48 AGPR, xr[6]=24 VGPR -> ~120 total ->
// 4 waves/SIMD. 64-row blocks (grid 1568), 4 waves, W SINGLE-buffered
// (LDS 32 KB -> >=4 independent blocks/CU whose TLP hides the per-chunk
// __syncthreads drain, m97-style). FC1 swapped (mfma(W1,X) -> H^T) so gelu
// packs to one b64 Hs write and Hs[m][h] is directly FC2's A-fragment.
__global__ __launch_bounds__(256, 4)
void mlp_k(const __hip_bfloat16* __restrict__ A,      // y2 [100352][192] bf16
           const __hip_bfloat16* __restrict__ W1t,    // [768][192] bf16 (n-major)
           const __hip_bfloat16* __restrict__ W2t,    // [192][768] bf16 (n-major)
           const float* __restrict__ b1,
           const float* __restrict__ b2,
           float* __restrict__ out)                   // x1, in-place += mlp
{
    __shared__ __align__(16) __hip_bfloat16 W1s[6][32][32];   // 12 KB (single buf)
    __shared__ __align__(16) __hip_bfloat16 W2s[192][32];     // 12 KB (single buf)
    __shared__ __align__(16) __hip_bfloat16 Hs[64][40];       // 5 KB, 80B stride
    __shared__ __align__(16) float b1s[768];                  // 3 KB

    const int tid  = threadIdx.x;
    const int lane = tid & 63, wave = tid >> 6;        // wave 0..3
    const int quad = lane >> 4, l15 = lane & 15;
    const int m0 = blockIdx.x * 64;
    const int arow = lane >> 2, acol = (lane & 3) * 8;

    // b1 -> LDS once (first __syncthreads drains it).
    if (tid < 192) ((fx4*)b1s)[tid] = ((const fx4*)b1)[tid];

    // X fragments in registers: 1 row-tile x 6 k-chunks (24 VGPR).
    bh8 xr[6];
    const __hip_bfloat16* xg = A + (size_t)(m0 + wave * 16 + l15) * 192 + quad * 8;
#pragma unroll
    for (int kc = 0; kc < 6; kc++) xr[kc] = *(const bh8*)(xg + kc * 32);

    // stage one 32-hidden chunk: W1 (32x192) + W2 (192x32) = 24 gloads,
    // 6 per wave.
    auto stage = [&](int c) {
#pragma unroll
        for (int i = 0; i < 6; i++) {
            const int g = wave * 6 + i;                // 0..23
            if (g < 12) {
                const int kc = g >> 1, half = g & 1;
                gload16(W1t + (size_t)(c * 32 + half * 16 + arow) * 192 + kc * 32 + acol,
                        &W1s[kc][half * 16][0]);
            } else {
                const int g2 = g - 12;                 // 0..11
                gload16(W2t + (size_t)(g2 * 16 + arow) * 768 + c * 32 + acol,
                        &W2s[g2 * 16][0]);
            }
        }
    };

    fx4 acc2[12];
#pragma unroll
    for (int nt = 0; nt < 12; nt++) acc2[nt] = {0.f, 0.f, 0.f, 0.f};

    stage(0);

    for (int c = 0; c < 24; ++c) {
        __syncthreads();     // drains staging (vmcnt) + b1/Hs (lgkm): chunk c ready

        // bias frags for this chunk (hidden-major: 4 consecutive h per reg)
        fx4 bv0 = *(const fx4*)&b1s[c * 32 + quad * 4];
        fx4 bv1 = *(const fx4*)&b1s[c * 32 + 16 + quad * 4];

        // ---- FC1 swapped: acc1[ni] = H^T tile, K=192, X from registers ----
        fx4 acc1[2];
        acc1[0] = {0.f, 0.f, 0.f, 0.f};
        acc1[1] = {0.f, 0.f, 0.f, 0.f};
#pragma unroll
        for (int kc = 0; kc < 6; kc++) {
#pragma unroll
            for (int ni = 0; ni < 2; ni++) {
                bh8 w = *(const bh8*)&W1s[kc][ni * 16 + l15][quad * 8];
                acc1[ni] = mfma_bf16(w, xr[kc], acc1[ni]);
            }
        }

        // ---- bias + gelu + pack -> Hs[m][h] (one b64 write per ni) ----
#pragma unroll
        for (int ni = 0; ni < 2; ni++) {
            const fx4 bv = ni ? bv1 : bv0;
            sh4 pk;
#pragma unroll
            for (int r = 0; r < 4; r++) {
                float v = acc1[ni][r] + bv[r];
                float h = 0.5f * v * (1.0f + fast_erf(v * 0.70710678118654752f));
                union { __hip_bfloat16 hb; short s; } u;
                u.hb = __float2bfloat16(h);
                pk[r] = u.s;
            }
            *(sh4*)&Hs[wave * 16 + l15][ni * 16 + quad * 4] = pk;
        }
        LGKM0;               // wave-private Hs write->read handoff

        // ---- FC2: acc2 += H-chunk @ W2-chunk (K=32) ----
        bh8 ha = *(const bh8*)&Hs[wave * 16 + l15][quad * 8];
#pragma unroll
        for (int nt = 0; nt < 12; nt++) {
            bh8 w2 = *(const bh8*)&W2s[nt * 16 + l15][quad * 8];
            acc2[nt] = mfma_bf16(ha, w2, acc2[nt]);
        }

        __syncthreads();     // all waves done reading W; safe to restage
        if (c < 23) stage(c + 1);
    }

    // ---- epilogue: += b2 + residual (x1 already in out), fp32 in-place ----
#pragma unroll
    for (int nt = 0; nt < 12; nt++) {
        const int n = nt * 16 + l15;
        const float bn = b2[n];
#pragma unroll
        for (int r = 0; r < 4; r++) {
            const int m = m0 + wave * 16 + quad * 4 + r;
            out[(size_t)m * 192 + n] += acc2[nt][r] + bn;
        }
    }
}

// ---------------- proj + residual + LN2 fused: tile 64 x 192 (full row) ----------------
// x1out = A*Wt + pb + xresid (fp32, -> d_out); y2out = LN(x1out)*g2+b2 (bf16)
__global__ __launch_bounds__(256)
void projln_k(const __hip_bfloat16* __restrict__ A,
              const __hip_bfloat16* __restrict__ Bt,
              const float* __restrict__ pb,
              const float* __restrict__ xresid,
              const float* __restrict__ g2,
              const float* __restrict__ b2,
              float* __restrict__ x1out,
              __hip_bfloat16* __restrict__ y2out)
{
    __shared__ __align__(16) __hip_bfloat16 As[64 * 32];    // 4 KB
    __shared__ __align__(16) __hip_bfloat16 Bs[192 * 32];   // 12 KB
    const int tid  = threadIdx.x;
    const int lane = tid & 63, wave = tid >> 6;
    const int quad = lane >> 4, l15 = lane & 15;
    const int m0 = blockIdx.x * 64;

    const int arow = lane >> 2, acol = (lane & 3) * 8;
    const __hip_bfloat16* Ag = A + (size_t)(m0 + wave * 16 + arow) * 192 + acol;
    __hip_bfloat16* Al = &As[(wave * 16) * 32];
    const __hip_bfloat16* Bg0 = Bt + (size_t)((wave + 0) * 16 + arow) * 192 + acol;
    const __hip_bfloat16* Bg1 = Bt + (size_t)((wave + 4) * 16 + arow) * 192 + acol;
    const __hip_bfloat16* Bg2 = Bt + (size_t)((wave + 8) * 16 + arow) * 192 + acol;
    __hip_bfloat16* Bl0 = &Bs[((wave + 0) * 16) * 32];
    __hip_bfloat16* Bl1 = &Bs[((wave + 4) * 16) * 32];
    __hip_bfloat16* Bl2 = &Bs[((wave + 8) * 16) * 32];

    fx4 acc[12];
#pragma unroll
    for (int ct = 0; ct < 12; ct++) acc[ct] = {0.f, 0.f, 0.f, 0.f};

    for (int k0 = 0; k0 < 192; k0 += 32) {
        gload16(Ag  + k0, Al);
        gload16(Bg0 + k0, Bl0);
        gload16(Bg1 + k0, Bl1);
        gload16(Bg2 + k0, Bl2);
        __syncthreads();
        bh8 a = *(const bh8*)&As[(wave * 16 + l15) * 32 + quad * 8];
#pragma unroll
        for (int ct = 0; ct < 12; ct++) {
            bh8 b = *(const bh8*)&Bs[(ct * 16 + l15) * 32 + quad * 8];
            acc[ct] = mfma_bf16(a, b, acc[ct]);
        }
        __syncthreads();
    }

#pragma unroll
    for (int r = 0; r < 4; r++) {
        const int row = m0 + wave * 16 + quad * 4 + r;
        float vv[12];
        float s = 0.f, q = 0.f;
#pragma unroll
        for (int ct = 0; ct < 12; ct++) {
            const int col = ct * 16 + l15;
            float v = acc[ct][r] + pb[col] + xresid[(size_t)row * 192 + col];
            vv[ct] = v;
            x1out[(size_t)row * 192 + col] = v;
            s += v;
            q += v * v;
        }
        s += __shfl_xor(s, 1, 64);  q += __shfl_xor(q, 1, 64);
        s += __shfl_xor(s, 2, 64);  q += __shfl_xor(q, 2, 64);
        s += __shfl_xor(s, 4, 64);  q += __shfl_xor(q, 4, 64);
        s += __shfl_xor(s, 8, 64);  q += __shfl_xor(q, 8, 64);
        float mean = s * (1.0f / 192.0f);
        float var  = q * (1.0f / 192.0f) - mean * mean;
        float rstd = rsqrtf(var + 1e-5f);
#pragma unroll
        for (int ct = 0; ct < 12; ct++) {
            const int col = ct * 16 + l15;
            float y = (vv[ct] - mean) * rstd * g2[col] + b2[col];
            y2out[(size_t)row * 192 + col] = __float2bfloat16(y);
        }
    }
}

// ---------------- attention: one block per (window, head) ----------------
__global__ __launch_bounds__(256)
void attn_k(const __hip_bfloat16* __restrict__ qkv,   // [2048][49][576]
            const float* __restrict__ bias_table,
            __hip_bfloat16* __restrict__ aout)        // orig token order
{
    __shared__ __align__(16) __hip_bfloat16 Qb[64 * 32];
    __shared__ __align__(16) __hip_bfloat16 Kb[64 * 32];
    __shared__ __align__(16) __hip_bfloat16 Vt[32 * 64];   // Vt[d][m]
    __shared__ __align__(16) __hip_bfloat16 Ps[64 * 72];   // padded stride 72
    __shared__ float bias_h[169];

    const int tid  = threadIdx.x;
    const int lane = tid & 63, wave = tid >> 6;
    const int quad = lane >> 4, l15 = lane & 15;
    const int w = blockIdx.x / 6, hd = blockIdx.x % 6;
    const int b = w >> 6, wrem = w & 63, wi = wrem >> 3, wj = wrem & 7;
    const size_t base = (size_t)w * 49 * 576 + hd * 32;

    if (tid < 169) bias_h[tid] = bias_table[tid * 6 + hd];

    bh8 z = {0, 0, 0, 0, 0, 0, 0, 0};
    {
        int row = tid >> 2, ch = (tid & 3) * 8;
        if (row < 49) {
            *(bh8*)&Qb[row * 32 + ch] = *(const bh8*)(qkv + base + (size_t)row * 576 + ch);
            *(bh8*)&Kb[row * 32 + ch] = *(const bh8*)(qkv + base + (size_t)row * 576 + 192 + ch);
        } else {
            *(bh8*)&Qb[row * 32 + ch] = z;
            *(bh8*)&Kb[row * 32 + ch] = z;
        }
        *(bh8*)&Vt[tid * 8] = z;    // zero all of Vt
    }
    __syncthreads();
    for (int idx = tid; idx < 49 * 32; idx += 256) {       // V transpose scatter
        int n = idx >> 5, d = idx & 31;
        Vt[d * 64 + n] = qkv[base + (size_t)n * 576 + 384 + d];
    }
    __syncthreads();

    // ---- scores S = Q K^T ----
    fx4 zf = {0.f, 0.f, 0.f, 0.f};
    bh8 aq = *(const bh8*)&Qb[(wave * 16 + l15) * 32 + quad * 8];
    fx4 sarr[4];
#pragma unroll
    for (int ni = 0; ni < 4; ni++) {
        bh8 bk = *(const bh8*)&Kb[(ni * 16 + l15) * 32 + quad * 8];
        sarr[ni] = mfma_bf16(aq, bk, zf);
    }

    // ---- bias + mask + softmax ----
    int iarr[4], ria[4], cia[4], mbi[4];
#pragma unroll
    for (int r = 0; r < 4; r++) {
        int i = wave * 16 + quad * 4 + r;
        int ri = i / 7, ci = i - ri * 7;
        iarr[r] = i; ria[r] = ri; cia[r] = ci;
        int ar = wi * 7 + ri, ac = wj * 7 + ci;
        int br = (ar < 49) ? 0 : ((ar < 53) ? 1 : 2);
        int bc = (ac < 49) ? 0 : ((ac < 53) ? 1 : 2);
        mbi[r] = br * 3 + bc;
    }
    float vals[4][4];   // [ni][r]
#pragma unroll
    for (int ni = 0; ni < 4; ni++) {
        int jcol = ni * 16 + l15;
        int rj = jcol / 7, cj = jcol - rj * 7;
        int ar = wi * 7 + rj, ac = wj * 7 + cj;
        int br = (ar < 49) ? 0 : ((ar < 53) ? 1 : 2);
        int bc = (ac < 49) ? 0 : ((ac < 53) ? 1 : 2);
        int mbj = br * 3 + bc;
#pragma unroll
        for (int r = 0; r < 4; r++) {
            float v;
            if (jcol >= 49)            v = -1e30f;
            else if (iarr[r] >= 49)    v = 0.0f;
            else {
                int bidx = (ria[r] - rj + 6) * 13 + (cia[r] - cj + 6);
                v = sarr[ni][r] + bias_h[bidx] + ((mbi[r] != mbj) ? -100.0f : 0.0f);
            }
            vals[ni][r] = v;
        }
    }
#pragma unroll
    for (int r = 0; r < 4; r++) {
        float mx = fmaxf(fmaxf(vals[0][r], vals[1][r]), fmaxf(vals[2][r], vals[3][r]));
        mx = fmaxf(mx, __shfl_xor(mx, 1, 64));
        mx = fmaxf(mx, __shfl_xor(mx, 2, 64));
        mx = fmaxf(mx, __shfl_xor(mx, 4, 64));
        mx = fmaxf(mx, __shfl_xor(mx, 8, 64));
        float e0 = __expf(vals[0][r] - mx);
        float e1 = __expf(vals[1][r] - mx);
        float e2 = __expf(vals[2][r] - mx);
        float e3 = __expf(vals[3][r] - mx);
        float sm = e0 + e1 + e2 + e3;
        sm += __shfl_xor(sm, 1, 64);
        sm += __shfl_xor(sm, 2, 64);
        sm += __shfl_xor(sm, 4, 64);
        sm += __shfl_xor(sm, 8, 64);
        float inv = 1.0f / sm;
        int prow = (wave * 16 + quad * 4 + r) * 72;
        Ps[prow + 0 * 16 + l15] = __float2bfloat16(e0 * inv);
        Ps[prow + 1 * 16 + l15] = __float2bfloat16(e1 * inv);
        Ps[prow + 2 * 16 + l15] = __float2bfloat16(e2 * inv);
        Ps[prow + 3 * 16 + l15] = __float2bfloat16(e3 * inv);
    }
    __syncthreads();

    // ---- O = P V ----
    fx4 o0 = zf, o1 = zf;
#pragma unroll
    for (int k0 = 0; k0 < 64; k0 += 32) {
        bh8 ap  = *(const bh8*)&Ps[(wave * 16 + l15) * 72 + k0 + quad * 8];
        bh8 bv0 = *(const bh8*)&Vt[(l15)      * 64 + k0 + quad * 8];
        bh8 bv1 = *(const bh8*)&Vt[(16 + l15) * 64 + k0 + quad * 8];
        o0 = mfma_bf16(ap, bv0, o0);
        o1 = mfma_bf16(ap, bv1, o1);
    }

    // ---- write out in ORIGINAL token order ----
#pragma unroll
    for (int r = 0; r < 4; r++) {
        int m = wave * 16 + quad * 4 + r;
        if (m < 49) {
            int i = m / 7, j2 = m - i * 7;
            int orow = wi * 7 + i + 3;  if (orow >= 56) orow -= 56;
            int ocol = wj * 7 + j2 + 3; if (ocol >= 56) ocol -= 56;
            size_t t = (size_t)b * 3136 + orow * 56 + ocol;
            aout[t * 192 + hd * 32 + l15]      = __float2bfloat16(o0[r]);
            aout[t * 192 + hd * 32 + 16 + l15] = __float2bfloat16(o1[r]);
        }
    }
}

// ---------------- launch ----------------
// Layout (peak 193.6 MB):
//   buf1 @ 0          38,535,168 B : xw (window order) -> attn_out (orig order) -> y2
//   buf2 @ 38,535,168 154,140,672 B: qkv full (115.6 MB)
//   weights @ 192,675,840 .. 193,560,576
//   x1 lives in d_out (fp32); mlp_k does in-place owner-computes residual add on d_out.
extern "C" void kernel_launch(void* const* d_in, const int* in_sizes, int n_in,
                              void* d_out, int out_size, void* d_ws, size_t ws_size,
                              hipStream_t stream)
{
    const float* x      = (const float*)d_in[0];
    const float* n1g    = (const float*)d_in[1];
    const float* n1b    = (const float*)d_in[2];
    const float* qkv_w  = (const float*)d_in[3];
    const float* qkv_b  = (const float*)d_in[4];
    const float* proj_w = (const float*)d_in[5];
    const float* proj_b = (const float*)d_in[6];
    const float* btab   = (const float*)d_in[7];
    const float* n2g    = (const float*)d_in[8];
    const float* n2b    = (const float*)d_in[9];
    const float* fc1_w  = (const float*)d_in[10];
    const float* fc1_b  = (const float*)d_in[11];
    const float* fc2_w  = (const float*)d_in[12];
    const float* fc2_b  = (const float*)d_in[13];

    char* ws = (char*)d_ws;
    __hip_bfloat16* buf1    = (__hip_bfloat16*)(ws + 0);           // 38,535,168 B
    __hip_bfloat16* buf2    = (__hip_bfloat16*)(ws + 38535168);    // 154,140,672 B
    __hip_bfloat16* wt_qkv  = (__hip_bfloat16*)(ws + 192675840);   // 221,184 B
    __hip_bfloat16* wt_proj = (__hip_bfloat16*)(ws + 192897024);   // 73,728 B
    __hip_bfloat16* wt_fc1  = (__hip_bfloat16*)(ws + 192970752);   // 294,912 B
    __hip_bfloat16* wt_fc2  = (__hip_bfloat16*)(ws + 193265664);   // 294,912 B
    float*          x1      = (float*)d_out;                       // 77,070,336 B

    convw_k<<<dim3(432), 256, 0, stream>>>(qkv_w, wt_qkv, 192, 576);
    convw_k<<<dim3(144), 256, 0, stream>>>(proj_w, wt_proj, 192, 192);
    convw_k<<<dim3(576), 256, 0, stream>>>(fc1_w, wt_fc1, 192, 768);
    convw_k<<<dim3(576), 256, 0, stream>>>(fc2_w, wt_fc2, 768, 192);

    // LN1 + shift + window partition: 100352 tokens -> buf1 (bf16, window order)
    ln1_gather_k<<<dim3(25088), 256, 0, stream>>>(x, n1g, n1b, buf1);

    // QKV: [100352 x 192] x [576 x 192]^T -> buf2 (bf16)
    gemm2_k<0, 192, 576><<<dim3(784, 9), 256, 0, stream>>>(buf1, wt_qkv, qkv_b, nullptr, buf2);

    // attention: 2048 windows x 6 heads -> buf1 (bf16, orig token order)
    attn_k<<<dim3(12288), 256, 0, stream>>>(buf2, btab, buf1);

    // proj + residual + LN2: x1 -> d_out (fp32), y2 -> buf1 (bf16, in-place over attn_out)
    projln_k<<<dim3(1568), 256, 0, stream>>>(buf1, wt_proj, proj_b, x, n2g, n2b, x1, buf1);

    // fused FC1 + gelu + FC2 + residual (in-place on d_out), 64 rows/block
    mlp_k<<<dim3(1568), 256, 0, stream>>>(buf1, wt_fc1, wt_fc2, fc1_b, fc2_b, x1);
}

// Round 9
// 459.767 us; speedup vs baseline: 1.1183x; 1.1183x over previous
//
#include <hip/hip_runtime.h>
#include <hip/hip_bf16.h>
#include <math.h>

typedef __attribute__((ext_vector_type(8))) short bh8;
typedef __attribute__((ext_vector_type(4))) short sh4;
typedef __attribute__((ext_vector_type(4))) float fx4;

__device__ __forceinline__ fx4 mfma_bf16(bh8 a, bh8 b, fx4 c) {
    return __builtin_amdgcn_mfma_f32_16x16x32_bf16(a, b, c, 0, 0, 0);
}

// async global->LDS, 16B per lane. LDS dest = wave-uniform base + lane*16.
__device__ __forceinline__ void gload16(const __hip_bfloat16* g, __hip_bfloat16* l) {
    __builtin_amdgcn_global_load_lds(
        (const __attribute__((address_space(1))) void*)g,
        (__attribute__((address_space(3))) void*)l,
        16, 0, 0);
}

// branchless erf, Abramowitz-Stegun 7.1.26, |abs err| <= 1.5e-7 (<< bf16 rounding).
__device__ __forceinline__ float fast_erf(float u) {
    float au = fabsf(u);
    float t  = __builtin_amdgcn_rcpf(1.0f + 0.3275911f * au);
    float p  = ((((1.061405429f * t - 1.453152027f) * t + 1.421413741f) * t
                 - 0.284496736f) * t + 0.254829592f) * t;
    float e  = __expf(-u * u);
    return copysignf(1.0f - p * e, u);
}

// sync/wait primitives (T4 counted-vmcnt, m218). sched_barrier(0) after each
// asm wait: hipcc hoists register-only MFMA past inline-asm waitcnt (rule #18).
#define WAITV6 do { asm volatile("s_waitcnt vmcnt(6)" ::: "memory"); \
                    __builtin_amdgcn_sched_barrier(0); } while (0)
#define WAITV0 do { asm volatile("s_waitcnt vmcnt(0)" ::: "memory"); \
                    __builtin_amdgcn_sched_barrier(0); } while (0)
#define LGKM0  do { asm volatile("s_waitcnt lgkmcnt(0)" ::: "memory"); \
                    __builtin_amdgcn_sched_barrier(0); } while (0)
#define BARR   do { __builtin_amdgcn_s_barrier(); \
                    __builtin_amdgcn_sched_barrier(0); } while (0)

// ---------------- merged weight convert+transpose (one launch for all 4) ----------------
// qkv 192x576=110592 | proj 192x192=36864 | fc1 192x768=147456 | fc2 768x192=147456
__global__ __launch_bounds__(256)
void convw_all_k(const float* __restrict__ qkv_w, const float* __restrict__ proj_w,
                 const float* __restrict__ fc1_w, const float* __restrict__ fc2_w,
                 __hip_bfloat16* __restrict__ wq, __hip_bfloat16* __restrict__ wp,
                 __hip_bfloat16* __restrict__ w1, __hip_bfloat16* __restrict__ w2)
{
    int idx = blockIdx.x * 256 + threadIdx.x;
    if (idx < 110592) {
        int k = idx / 576, n = idx - k * 576;
        wq[(size_t)n * 192 + k] = __float2bfloat16(qkv_w[idx]);
        return;
    }
    idx -= 110592;
    if (idx < 36864) {
        int k = idx / 192, n = idx - k * 192;
        wp[(size_t)n * 192 + k] = __float2bfloat16(proj_w[idx]);
        return;
    }
    idx -= 36864;
    if (idx < 147456) {
        int k = idx / 768, n = idx - k * 768;
        w1[(size_t)n * 192 + k] = __float2bfloat16(fc1_w[idx]);
        return;
    }
    idx -= 147456;
    if (idx < 147456) {
        int k = idx / 192, n = idx - k * 192;
        w2[(size_t)n * 768 + k] = __float2bfloat16(fc2_w[idx]);
    }
}

// ---------------- LN1 + shift + window-partition gather -> xw bf16 (window order) -------
__global__ __launch_bounds__(256)
void ln1_gather_k(const float* __restrict__ x, const float* __restrict__ g,
                  const float* __restrict__ bia, __hip_bfloat16* __restrict__ xw)
{
    const int wave = threadIdx.x >> 6, lane = threadIdx.x & 63;
    const int t = blockIdx.x * 4 + wave;        // window-ordered token, < 100352
    const int w = t / 49, n = t - w * 49;
    const int b = w >> 6, wrem = w & 63, wi = wrem >> 3, wj = wrem & 7;
    const int i = n / 7, j = n - i * 7;
    int sr = wi * 7 + i + 3; if (sr >= 56) sr -= 56;
    int sc = wj * 7 + j + 3; if (sc >= 56) sc -= 56;
    const float* xp = x + ((size_t)b * 3136 + sr * 56 + sc) * 192;
    float v0 = xp[lane], v1 = xp[lane + 64], v2 = xp[lane + 128];
    float s = v0 + v1 + v2;
    float q = v0 * v0 + v1 * v1 + v2 * v2;
    for (int off = 32; off > 0; off >>= 1) {
        s += __shfl_down(s, off, 64);
        q += __shfl_down(q, off, 64);
    }
    s = __shfl(s, 0, 64); q = __shfl(q, 0, 64);
    float mean = s * (1.0f / 192.0f);
    float var  = q * (1.0f / 192.0f) - mean * mean;
    float rstd = rsqrtf(var + 1e-5f);
    __hip_bfloat16* op = xw + (size_t)t * 192;
    op[lane]       = __float2bfloat16((v0 - mean) * rstd * g[lane]       + bia[lane]);
    op[lane + 64]  = __float2bfloat16((v1 - mean) * rstd * g[lane + 64]  + bia[lane + 64]);
    op[lane + 128] = __float2bfloat16((v2 - mean) * rstd * g[lane + 128] + bia[lane + 128]);
}

// ---------------- GEMM (QKV): 128x64 tile, global_load_lds staging ----------------
// 1-D grid, XCD-chunked swizzle (T1): the NOUT/64 col-blocks of one row-tile run
// temporally adjacent on ONE XCD -> the 128x192 A-tile stays L2-hot across its
// 9 re-reads (R0 counters showed FC1-style re-reads going to HBM).
// Requires gridDim.x % 8 == 0 (7056 = 882*8, bijective).
template<int K, int NOUT>
__global__ __launch_bounds__(256)
void gemm_qkv_k(const __hip_bfloat16* __restrict__ A,
                const __hip_bfloat16* __restrict__ Bt,
                const float* __restrict__ bias,
                __hip_bfloat16* __restrict__ outv)
{
    __shared__ __align__(16) __hip_bfloat16 As[128 * 32];   // 8 KB
    __shared__ __align__(16) __hip_bfloat16 Bs[64 * 32];    // 4 KB
    const int tid  = threadIdx.x;
    const int lane = tid & 63, wave = tid >> 6;
    const int quad = lane >> 4, l15 = lane & 15;

    const int nb = NOUT / 64;
    const int wk = (blockIdx.x & 7) * ((int)gridDim.x >> 3) + ((int)blockIdx.x >> 3);
    const int m0 = (wk / nb) * 128, n0 = (wk % nb) * 64;

    const int arow = lane >> 2, acol = (lane & 3) * 8;
    const __hip_bfloat16* Ag0 = A  + (size_t)(m0 + wave * 32 + arow)      * K + acol;
    const __hip_bfloat16* Ag1 = A  + (size_t)(m0 + wave * 32 + 16 + arow) * K + acol;
    const __hip_bfloat16* Bg  = Bt + (size_t)(n0 + wave * 16 + arow)      * K + acol;
    __hip_bfloat16* Al0 = &As[(wave * 32)      * 32];
    __hip_bfloat16* Al1 = &As[(wave * 32 + 16) * 32];
    __hip_bfloat16* Bl  = &Bs[(wave * 16)      * 32];

    fx4 acc[2][4];
#pragma unroll
    for (int mi = 0; mi < 2; mi++)
#pragma unroll
        for (int ni = 0; ni < 4; ni++) acc[mi][ni] = {0.f, 0.f, 0.f, 0.f};

    for (int k0 = 0; k0 < K; k0 += 32) {
        gload16(Ag0 + k0, Al0);
        gload16(Ag1 + k0, Al1);
        gload16(Bg  + k0, Bl);
        __syncthreads();
        bh8 a0 = *(const bh8*)&As[(wave * 32 + l15)      * 32 + quad * 8];
        bh8 a1 = *(const bh8*)&As[(wave * 32 + 16 + l15) * 32 + quad * 8];
        bh8 b0 = *(const bh8*)&Bs[(0 * 16 + l15) * 32 + quad * 8];
        bh8 b1 = *(const bh8*)&Bs[(1 * 16 + l15) * 32 + quad * 8];
        bh8 b2 = *(const bh8*)&Bs[(2 * 16 + l15) * 32 + quad * 8];
        bh8 b3 = *(const bh8*)&Bs[(3 * 16 + l15) * 32 + quad * 8];
        acc[0][0] = mfma_bf16(a0, b0, acc[0][0]);
        acc[0][1] = mfma_bf16(a0, b1, acc[0][1]);
        acc[0][2] = mfma_bf16(a0, b2, acc[0][2]);
        acc[0][3] = mfma_bf16(a0, b3, acc[0][3]);
        acc[1][0] = mfma_bf16(a1, b0, acc[1][0]);
        acc[1][1] = mfma_bf16(a1, b1, acc[1][1]);
        acc[1][2] = mfma_bf16(a1, b2, acc[1][2]);
        acc[1][3] = mfma_bf16(a1, b3, acc[1][3]);
        __syncthreads();
    }

#pragma unroll
    for (int mi = 0; mi < 2; mi++)
#pragma unroll
    for (int ni = 0; ni < 4; ni++) {
        const int n = n0 + ni * 16 + l15;
        const float bn = bias[n];
#pragma unroll
        for (int r = 0; r < 4; r++) {
            const int m = m0 + wave * 32 + mi * 16 + quad * 4 + r;
            float v = acc[mi][ni][r] + bn;
            if (n < 192) v *= 0.17677669529663687f;   // SCALE = 32^-0.5 on q
            outv[(size_t)m * NOUT + n] = __float2bfloat16(v);
        }
    }
}

// ---------------- fused MLP (R4-exact, best measured: 148 us) ----------------
// 128 rows/block (grid 784), 4 waves, each wave owns 32 rows (2 row-tiles).
// Hidden in 24 chunks of 32, W1/W2 double-buffered, counted vmcnt(6) (T4):
// next chunk's 6 wave-stage-loads stay in flight across both barriers.
// FC1 computed SWAPPED: mfma(W1frag, Xfrag) -> D[h][m] = H^T tile, so the 4
// accumulator regs are 4 CONSECUTIVE hidden indices of one row -> gelu packs
// into one ds_write_b64, and Hs[m][h] row-major is directly FC2's A-fragment.
// b1 lives in LDS (no register rotation -> no hidden vmcnt(0) drains).
// NOTE: occupancy is register-capped (~108 VGPR + 96 AGPR acc2 -> 2 waves/SIMD);
// R7/R8 proved neither more waves/barrier nor higher occupancy beats this.
__global__ __launch_bounds__(256, 2)
void mlp_k(const __hip_bfloat16* __restrict__ A,      // y2 [100352][192] bf16
           const __hip_bfloat16* __restrict__ W1t,    // [768][192] bf16 (n-major)
           const __hip_bfloat16* __restrict__ W2t,    // [192][768] bf16 (n-major)
           const float* __restrict__ b1,
           const float* __restrict__ b2,
           float* __restrict__ out)                   // x1, in-place += mlp
{
    __shared__ __align__(16) __hip_bfloat16 W1s[2][6][32][32];  // 24 KB
    __shared__ __align__(16) __hip_bfloat16 W2s[2][192][32];    // 24 KB
    __shared__ __align__(16) __hip_bfloat16 Hs[128][40];        // 10 KB, 80B stride
    __shared__ __align__(16) float b1s[768];                    // 3 KB

    const int tid  = threadIdx.x;
    const int lane = tid & 63, wave = tid >> 6;
    const int quad = lane >> 4, l15 = lane & 15;
    const int m0 = blockIdx.x * 128;
    const int arow = lane >> 2, acol = (lane & 3) * 8;

    // b1 -> LDS once (192 threads x 16B). Drain ds_write before first barrier.
    if (tid < 192) ((fx4*)b1s)[tid] = ((const fx4*)b1)[tid];
    LGKM0;

    // X fragments in registers: 2 row-tiles x 6 k-chunks (48 VGPR).
    bh8 xr[2][6];
    const __hip_bfloat16* xg = A + (size_t)(m0 + wave * 32 + l15) * 192 + quad * 8;
#pragma unroll
    for (int rt = 0; rt < 2; rt++)
#pragma unroll
        for (int kc = 0; kc < 6; kc++)
            xr[rt][kc] = *(const bh8*)(xg + rt * 16 * 192 + kc * 32);

    // stage one 32-hidden chunk: W1 (32x192) + W2 (192x32), 6 gloads/wave.
    auto stage = [&](int bf, int c) {
#pragma unroll
        for (int i = 0; i < 3; i++) {
            const int g = wave * 3 + i;
            const int kc = g >> 1, half = g & 1;
            gload16(W1t + (size_t)(c * 32 + half * 16 + arow) * 192 + kc * 32 + acol,
                    &W1s[bf][kc][half * 16][0]);
            gload16(W2t + (size_t)(g * 16 + arow) * 768 + c * 32 + acol,
                    &W2s[bf][g * 16][0]);
        }
    };

    fx4 acc2[2][12];
#pragma unroll
    for (int rt = 0; rt < 2; rt++)
#pragma unroll
        for (int nt = 0; nt < 12; nt++) acc2[rt][nt] = {0.f, 0.f, 0.f, 0.f};

    stage(0, 0);
    stage(1, 1);

    int cur = 0;
    for (int c = 0; c < 23; ++c) {
        WAITV6;            // my chunk-c stage done; chunk-(c+1)'s 6 ops stay in flight
        BARR;              // all waves' chunk-c loads landed in buf[cur]

        // bias frags for this chunk (hidden-major: 4 consecutive h per reg)
        fx4 bv0 = *(const fx4*)&b1s[c * 32 + quad * 4];
        fx4 bv1 = *(const fx4*)&b1s[c * 32 + 16 + quad * 4];

        // ---- FC1 swapped: acc1[rt][ni] = H^T tile, K=192, X from registers ----
        fx4 acc1[2][2];
        acc1[0][0] = {0.f, 0.f, 0.f, 0.f}; acc1[0][1] = {0.f, 0.f, 0.f, 0.f};
        acc1[1][0] = {0.f, 0.f, 0.f, 0.f}; acc1[1][1] = {0.f, 0.f, 0.f, 0.f};
        __builtin_amdgcn_s_setprio(1);
#pragma unroll
        for (int kc = 0; kc < 6; kc++) {
#pragma unroll
            for (int ni = 0; ni < 2; ni++) {
                bh8 w = *(const bh8*)&W1s[cur][kc][ni * 16 + l15][quad * 8];
                acc1[0][ni] = mfma_bf16(w, xr[0][kc], acc1[0][ni]);
                acc1[1][ni] = mfma_bf16(w, xr[1][kc], acc1[1][ni]);
            }
        }
        __builtin_amdgcn_s_setprio(0);

        // ---- bias + gelu + pack -> Hs[m][h] (one b64 write per tile) ----
#pragma unroll
        for (int rt = 0; rt < 2; rt++) {
#pragma unroll
            for (int ni = 0; ni < 2; ni++) {
                const fx4 bv = ni ? bv1 : bv0;
                sh4 pk;
#pragma unroll
                for (int r = 0; r < 4; r++) {
                    float v = acc1[rt][ni][r] + bv[r];
                    float h = 0.5f * v * (1.0f + fast_erf(v * 0.70710678118654752f));
                    union { __hip_bfloat16 hb; short s; } u;
                    u.hb = __float2bfloat16(h);
                    pk[r] = u.s;
                }
                *(sh4*)&Hs[wave * 32 + rt * 16 + l15][ni * 16 + quad * 4] = pk;
            }
        }
        LGKM0;             // wave-private Hs write->read handoff (no vm drain)

        // ---- FC2: acc2 += H-chunk @ W2-chunk (K=32) ----
        bh8 ha0 = *(const bh8*)&Hs[wave * 32 + l15][quad * 8];
        bh8 ha1 = *(const bh8*)&Hs[wave * 32 + 16 + l15][quad * 8];
        __builtin_amdgcn_s_setprio(1);
#pragma unroll
        for (int nt = 0; nt < 12; nt++) {
            bh8 w2 = *(const bh8*)&W2s[cur][nt * 16 + l15][quad * 8];
            acc2[0][nt] = mfma_bf16(ha0, w2, acc2[0][nt]);
            acc2[1][nt] = mfma_bf16(ha1, w2, acc2[1][nt]);
        }
        __builtin_amdgcn_s_setprio(0);

        BARR;              // all waves done reading buf[cur]; safe to restage it
        if (c < 22) stage(cur, c + 2);
        cur ^= 1;
    }

    // ---- peeled chunk 23 (drain once) ----
    {
        WAITV0;
        BARR;
        fx4 bv0 = *(const fx4*)&b1s[23 * 32 + 0 * 16 + quad * 4];
        fx4 bv1 = *(const fx4*)&b1s[23 * 32 + 1 * 16 + quad * 4];
        fx4 acc1[2][2];
        acc1[0][0] = {0.f, 0.f, 0.f, 0.f}; acc1[0][1] = {0.f, 0.f, 0.f, 0.f};
        acc1[1][0] = {0.f, 0.f, 0.f, 0.f}; acc1[1][1] = {0.f, 0.f, 0.f, 0.f};
#pragma unroll
        for (int kc = 0; kc < 6; kc++) {
#pragma unroll
            for (int ni = 0; ni < 2; ni++) {
                bh8 w = *(const bh8*)&W1s[cur][kc][ni * 16 + l15][quad * 8];
                acc1[0][ni] = mfma_bf16(w, xr[0][kc], acc1[0][ni]);
                acc1[1][ni] = mfma_bf16(w, xr[1][kc], acc1[1][ni]);
            }
        }
#pragma unroll
        for (int rt = 0; rt < 2; rt++) {
#pragma unroll
            for (int ni = 0; ni < 2; ni++) {
                const fx4 bv = ni ? bv1 : bv0;
                sh4 pk;
#pragma unroll
                for (int r = 0; r < 4; r++) {
                    float v = acc1[rt][ni][r] + bv[r];
                    float h = 0.5f * v * (1.0f + fast_erf(v * 0.70710678118654752f));
                    union { __hip_bfloat16 hb; short s; } u;
                    u.hb = __float2bfloat16(h);
                    pk[r] = u.s;
                }
                *(sh4*)&Hs[wave * 32 + rt * 16 + l15][ni * 16 + quad * 4] = pk;
            }
        }
        LGKM0;
        bh8 ha0 = *(const bh8*)&Hs[wave * 32 + l15][quad * 8];
        bh8 ha1 = *(const bh8*)&Hs[wave * 32 + 16 + l15][quad * 8];
#pragma unroll
        for (int nt = 0; nt < 12; nt++) {
            bh8 w2 = *(const bh8*)&W2s[cur][nt * 16 + l15][quad * 8];
            acc2[0][nt] = mfma_bf16(ha0, w2, acc2[0][nt]);
            acc2[1][nt] = mfma_bf16(ha1, w2, acc2[1][nt]);
        }
    }

    // ---- epilogue: += b2 + residual (x1 already in out), fp32 in-place ----
#pragma unroll
    for (int rt = 0; rt < 2; rt++)
#pragma unroll
    for (int nt = 0; nt < 12; nt++) {
        const int n = nt * 16 + l15;
        const float bn = b2[n];
#pragma unroll
        for (int r = 0; r < 4; r++) {
            const int m = m0 + wave * 32 + rt * 16 + quad * 4 + r;
            out[(size_t)m * 192 + n] += acc2[rt][nt][r] + bn;
        }
    }
}

// ---------------- proj + residual + LN2 fused: tile 64 x 192 (full row) ----------------
// x1out = A*Wt + pb + xresid (fp32, -> d_out); y2out = LN(x1out)*g2+b2 (bf16)
__global__ __launch_bounds__(256)
void projln_k(const __hip_bfloat16* __restrict__ A,
              const __hip_bfloat16* __restrict__ Bt,
              const float* __restrict__ pb,
              const float* __restrict__ xresid,
              const float* __restrict__ g2,
              const float* __restrict__ b2,
              float* __restrict__ x1out,
              __hip_bfloat16* __restrict__ y2out)
{
    __shared__ __align__(16) __hip_bfloat16 As[64 * 32];    // 4 KB
    __shared__ __align__(16) __hip_bfloat16 Bs[192 * 32];   // 12 KB
    const int tid  = threadIdx.x;
    const int lane = tid & 63, wave = tid >> 6;
    const int quad = lane >> 4, l15 = lane & 15;
    const int m0 = blockIdx.x * 64;

    const int arow = lane >> 2, acol = (lane & 3) * 8;
    const __hip_bfloat16* Ag = A + (size_t)(m0 + wave * 16 + arow) * 192 + acol;
    __hip_bfloat16* Al = &As[(wave * 16) * 32];
    const __hip_bfloat16* Bg0 = Bt + (size_t)((wave + 0) * 16 + arow) * 192 + acol;
    const __hip_bfloat16* Bg1 = Bt + (size_t)((wave + 4) * 16 + arow) * 192 + acol;
    const __hip_bfloat16* Bg2 = Bt + (size_t)((wave + 8) * 16 + arow) * 192 + acol;
    __hip_bfloat16* Bl0 = &Bs[((wave + 0) * 16) * 32];
    __hip_bfloat16* Bl1 = &Bs[((wave + 4) * 16) * 32];
    __hip_bfloat16* Bl2 = &Bs[((wave + 8) * 16) * 32];

    fx4 acc[12];
#pragma unroll
    for (int ct = 0; ct < 12; ct++) acc[ct] = {0.f, 0.f, 0.f, 0.f};

    for (int k0 = 0; k0 < 192; k0 += 32) {
        gload16(Ag  + k0, Al);
        gload16(Bg0 + k0, Bl0);
        gload16(Bg1 + k0, Bl1);
        gload16(Bg2 + k0, Bl2);
        __syncthreads();
        bh8 a = *(const bh8*)&As[(wave * 16 + l15) * 32 + quad * 8];
#pragma unroll
        for (int ct = 0; ct < 12; ct++) {
            bh8 b = *(const bh8*)&Bs[(ct * 16 + l15) * 32 + quad * 8];
            acc[ct] = mfma_bf16(a, b, acc[ct]);
        }
        __syncthreads();
    }

#pragma unroll
    for (int r = 0; r < 4; r++) {
        const int row = m0 + wave * 16 + quad * 4 + r;
        float vv[12];
        float s = 0.f, q = 0.f;
#pragma unroll
        for (int ct = 0; ct < 12; ct++) {
            const int col = ct * 16 + l15;
            float v = acc[ct][r] + pb[col] + xresid[(size_t)row * 192 + col];
            vv[ct] = v;
            x1out[(size_t)row * 192 + col] = v;
            s += v;
            q += v * v;
        }
        s += __shfl_xor(s, 1, 64);  q += __shfl_xor(q, 1, 64);
        s += __shfl_xor(s, 2, 64);  q += __shfl_xor(q, 2, 64);
        s += __shfl_xor(s, 4, 64);  q += __shfl_xor(q, 4, 64);
        s += __shfl_xor(s, 8, 64);  q += __shfl_xor(q, 8, 64);
        float mean = s * (1.0f / 192.0f);
        float var  = q * (1.0f / 192.0f) - mean * mean;
        float rstd = rsqrtf(var + 1e-5f);
#pragma unroll
        for (int ct = 0; ct < 12; ct++) {
            const int col = ct * 16 + l15;
            float y = (vv[ct] - mean) * rstd * g2[col] + b2[col];
            y2out[(size_t)row * 192 + col] = __float2bfloat16(y);
        }
    }
}

// ---------------- attention: one block per (window, head) ----------------
__global__ __launch_bounds__(256)
void attn_k(const __hip_bfloat16* __restrict__ qkv,   // [2048][49][576]
            const float* __restrict__ bias_table,
            __hip_bfloat16* __restrict__ aout)        // orig token order
{
    __shared__ __align__(16) __hip_bfloat16 Qb[64 * 32];
    __shared__ __align__(16) __hip_bfloat16 Kb[64 * 32];
    __shared__ __align__(16) __hip_bfloat16 Vt[32 * 64];   // Vt[d][m]
    __shared__ __align__(16) __hip_bfloat16 Ps[64 * 72];   // padded stride 72
    __shared__ float bias_h[169];

    const int tid  = threadIdx.x;
    const int lane = tid & 63, wave = tid >> 6;
    const int quad = lane >> 4, l15 = lane & 15;
    const int w = blockIdx.x / 6, hd = blockIdx.x % 6;
    const int b = w >> 6, wrem = w & 63, wi = wrem >> 3, wj = wrem & 7;
    const size_t base = (size_t)w * 49 * 576 + hd * 32;

    if (tid < 169) bias_h[tid] = bias_table[tid * 6 + hd];

    bh8 z = {0, 0, 0, 0, 0, 0, 0, 0};
    {
        int row = tid >> 2, ch = (tid & 3) * 8;
        if (row < 49) {
            *(bh8*)&Qb[row * 32 + ch] = *(const bh8*)(qkv + base + (size_t)row * 576 + ch);
            *(bh8*)&Kb[row * 32 + ch] = *(const bh8*)(qkv + base + (size_t)row * 576 + 192 + ch);
        } else {
            *(bh8*)&Qb[row * 32 + ch] = z;
            *(bh8*)&Kb[row * 32 + ch] = z;
        }
        *(bh8*)&Vt[tid * 8] = z;    // zero all of Vt
    }
    __syncthreads();
    for (int idx = tid; idx < 49 * 32; idx += 256) {       // V transpose scatter
        int n = idx >> 5, d = idx & 31;
        Vt[d * 64 + n] = qkv[base + (size_t)n * 576 + 384 + d];
    }
    __syncthreads();

    // ---- scores S = Q K^T ----
    fx4 zf = {0.f, 0.f, 0.f, 0.f};
    bh8 aq = *(const bh8*)&Qb[(wave * 16 + l15) * 32 + quad * 8];
    fx4 sarr[4];
#pragma unroll
    for (int ni = 0; ni < 4; ni++) {
        bh8 bk = *(const bh8*)&Kb[(ni * 16 + l15) * 32 + quad * 8];
        sarr[ni] = mfma_bf16(aq, bk, zf);
    }

    // ---- bias + mask + softmax ----
    int iarr[4], ria[4], cia[4], mbi[4];
#pragma unroll
    for (int r = 0; r < 4; r++) {
        int i = wave * 16 + quad * 4 + r;
        int ri = i / 7, ci = i - ri * 7;
        iarr[r] = i; ria[r] = ri; cia[r] = ci;
        int ar = wi * 7 + ri, ac = wj * 7 + ci;
        int br = (ar < 49) ? 0 : ((ar < 53) ? 1 : 2);
        int bc = (ac < 49) ? 0 : ((ac < 53) ? 1 : 2);
        mbi[r] = br * 3 + bc;
    }
    float vals[4][4];   // [ni][r]
#pragma unroll
    for (int ni = 0; ni < 4; ni++) {
        int jcol = ni * 16 + l15;
        int rj = jcol / 7, cj = jcol - rj * 7;
        int ar = wi * 7 + rj, ac = wj * 7 + cj;
        int br = (ar < 49) ? 0 : ((ar < 53) ? 1 : 2);
        int bc = (ac < 49) ? 0 : ((ac < 53) ? 1 : 2);
        int mbj = br * 3 + bc;
#pragma unroll
        for (int r = 0; r < 4; r++) {
            float v;
            if (jcol >= 49)            v = -1e30f;
            else if (iarr[r] >= 49)    v = 0.0f;
            else {
                int bidx = (ria[r] - rj + 6) * 13 + (cia[r] - cj + 6);
                v = sarr[ni][r] + bias_h[bidx] + ((mbi[r] != mbj) ? -100.0f : 0.0f);
            }
            vals[ni][r] = v;
        }
    }
#pragma unroll
    for (int r = 0; r < 4; r++) {
        float mx = fmaxf(fmaxf(vals[0][r], vals[1][r]), fmaxf(vals[2][r], vals[3][r]));
        mx = fmaxf(mx, __shfl_xor(mx, 1, 64));
        mx = fmaxf(mx, __shfl_xor(mx, 2, 64));
        mx = fmaxf(mx, __shfl_xor(mx, 4, 64));
        mx = fmaxf(mx, __shfl_xor(mx, 8, 64));
        float e0 = __expf(vals[0][r] - mx);
        float e1 = __expf(vals[1][r] - mx);
        float e2 = __expf(vals[2][r] - mx);
        float e3 = __expf(vals[3][r] - mx);
        float sm = e0 + e1 + e2 + e3;
        sm += __shfl_xor(sm, 1, 64);
        sm += __shfl_xor(sm, 2, 64);
        sm += __shfl_xor(sm, 4, 64);
        sm += __shfl_xor(sm, 8, 64);
        float inv = 1.0f / sm;
        int prow = (wave * 16 + quad * 4 + r) * 72;
        Ps[prow + 0 * 16 + l15] = __float2bfloat16(e0 * inv);
        Ps[prow + 1 * 16 + l15] = __float2bfloat16(e1 * inv);
        Ps[prow + 2 * 16 + l15] = __float2bfloat16(e2 * inv);
        Ps[prow + 3 * 16 + l15] = __float2bfloat16(e3 * inv);
    }
    __syncthreads();

    // ---- O = P V ----
    fx4 o0 = zf, o1 = zf;
#pragma unroll
    for (int k0 = 0; k0 < 64; k0 += 32) {
        bh8 ap  = *(const bh8*)&Ps[(wave * 16 + l15) * 72 + k0 + quad * 8];
        bh8 bv0 = *(const bh8*)&Vt[(l15)      * 64 + k0 + quad * 8];
        bh8 bv1 = *(const bh8*)&Vt[(16 + l15) * 64 + k0 + quad * 8];
        o0 = mfma_bf16(ap, bv0, o0);
        o1 = mfma_bf16(ap, bv1, o1);
    }

    // ---- write out in ORIGINAL token order ----
#pragma unroll
    for (int r = 0; r < 4; r++) {
        int m = wave * 16 + quad * 4 + r;
        if (m < 49) {
            int i = m / 7, j2 = m - i * 7;
            int orow = wi * 7 + i + 3;  if (orow >= 56) orow -= 56;
            int ocol = wj * 7 + j2 + 3; if (ocol >= 56) ocol -= 56;
            size_t t = (size_t)b * 3136 + orow * 56 + ocol;
            aout[t * 192 + hd * 32 + l15]      = __float2bfloat16(o0[r]);
            aout[t * 192 + hd * 32 + 16 + l15] = __float2bfloat16(o1[r]);
        }
    }
}

// ---------------- launch ----------------
// Layout (peak 193.6 MB):
//   buf1 @ 0          38,535,168 B : xw (window order) -> attn_out (orig order) -> y2
//   buf2 @ 38,535,168 154,140,672 B: qkv full (115.6 MB)
//   weights @ 192,675,840 .. 193,560,576
//   x1 lives in d_out (fp32); mlp_k does in-place owner-computes residual add on d_out.
extern "C" void kernel_launch(void* const* d_in, const int* in_sizes, int n_in,
                              void* d_out, int out_size, void* d_ws, size_t ws_size,
                              hipStream_t stream)
{
    const float* x      = (const float*)d_in[0];
    const float* n1g    = (const float*)d_in[1];
    const float* n1b    = (const float*)d_in[2];
    const float* qkv_w  = (const float*)d_in[3];
    const float* qkv_b  = (const float*)d_in[4];
    const float* proj_w = (const float*)d_in[5];
    const float* proj_b = (const float*)d_in[6];
    const float* btab   = (const float*)d_in[7];
    const float* n2g    = (const float*)d_in[8];
    const float* n2b    = (const float*)d_in[9];
    const float* fc1_w  = (const float*)d_in[10];
    const float* fc1_b  = (const float*)d_in[11];
    const float* fc2_w  = (const float*)d_in[12];
    const float* fc2_b  = (const float*)d_in[13];

    char* ws = (char*)d_ws;
    __hip_bfloat16* buf1    = (__hip_bfloat16*)(ws + 0);           // 38,535,168 B
    __hip_bfloat16* buf2    = (__hip_bfloat16*)(ws + 38535168);    // 154,140,672 B
    __hip_bfloat16* wt_qkv  = (__hip_bfloat16*)(ws + 192675840);   // 221,184 B
    __hip_bfloat16* wt_proj = (__hip_bfloat16*)(ws + 192897024);   // 73,728 B
    __hip_bfloat16* wt_fc1  = (__hip_bfloat16*)(ws + 192970752);   // 294,912 B
    __hip_bfloat16* wt_fc2  = (__hip_bfloat16*)(ws + 193265664);   // 294,912 B
    float*          x1      = (float*)d_out;                       // 77,070,336 B

    // all 4 weight converts in one launch (442368 elems)
    convw_all_k<<<dim3(1728), 256, 0, stream>>>(qkv_w, proj_w, fc1_w, fc2_w,
                                                wt_qkv, wt_proj, wt_fc1, wt_fc2);

    // LN1 + shift + window partition: 100352 tokens -> buf1 (bf16, window order)
    ln1_gather_k<<<dim3(25088), 256, 0, stream>>>(x, n1g, n1b, buf1);

    // QKV: [100352 x 192] x [576 x 192]^T -> buf2 (bf16), XCD-chunked swizzle
    gemm_qkv_k<192, 576><<<dim3(7056), 256, 0, stream>>>(buf1, wt_qkv, qkv_b, buf2);

    // attention: 2048 windows x 6 heads -> buf1 (bf16, orig token order)
    attn_k<<<dim3(12288), 256, 0, stream>>>(buf2, btab, buf1);

    // proj + residual + LN2: x1 -> d_out (fp32), y2 -> buf1 (bf16, in-place over attn_out)
    projln_k<<<dim3(1568), 256, 0, stream>>>(buf1, wt_proj, proj_b, x, n2g, n2b, x1, buf1);

    // fused FC1 + gelu + FC2 + residual (in-place on d_out), 128 rows/block
    mlp_k<<<dim3(784), 256, 0, stream>>>(buf1, wt_fc1, wt_fc2, fc1_b, fc2_b, x1);
}

// Round 10
// 444.197 us; speedup vs baseline: 1.1575x; 1.0351x over previous
//
#include <hip/hip_runtime.h>
#include <hip/hip_bf16.h>
#include <math.h>

typedef __attribute__((ext_vector_type(8))) short bh8;
typedef __attribute__((ext_vector_type(4))) short sh4;
typedef __attribute__((ext_vector_type(4))) float fx4;

__device__ __forceinline__ fx4 mfma_bf16(bh8 a, bh8 b, fx4 c) {
    return __builtin_amdgcn_mfma_f32_16x16x32_bf16(a, b, c, 0, 0, 0);
}

// async global->LDS, 16B per lane. LDS dest = wave-uniform base + lane*16.
__device__ __forceinline__ void gload16(const __hip_bfloat16* g, __hip_bfloat16* l) {
    __builtin_amdgcn_global_load_lds(
        (const __attribute__((address_space(1))) void*)g,
        (__attribute__((address_space(3))) void*)l,
        16, 0, 0);
}

// branchless erf, Abramowitz-Stegun 7.1.26, |abs err| <= 1.5e-7 (<< bf16 rounding).
__device__ __forceinline__ float fast_erf(float u) {
    float au = fabsf(u);
    float t  = __builtin_amdgcn_rcpf(1.0f + 0.3275911f * au);
    float p  = ((((1.061405429f * t - 1.453152027f) * t + 1.421413741f) * t
                 - 0.284496736f) * t + 0.254829592f) * t;
    float e  = __expf(-u * u);
    return copysignf(1.0f - p * e, u);
}

// sync/wait primitives (T4 counted-vmcnt, m218). sched_barrier(0) after each
// asm wait: hipcc hoists register-only MFMA past inline-asm waitcnt (rule #18).
#define WAITV6 do { asm volatile("s_waitcnt vmcnt(6)" ::: "memory"); \
                    __builtin_amdgcn_sched_barrier(0); } while (0)
#define WAITV0 do { asm volatile("s_waitcnt vmcnt(0)" ::: "memory"); \
                    __builtin_amdgcn_sched_barrier(0); } while (0)
#define LGKM0  do { asm volatile("s_waitcnt lgkmcnt(0)" ::: "memory"); \
                    __builtin_amdgcn_sched_barrier(0); } while (0)
#define BARR   do { __builtin_amdgcn_s_barrier(); \
                    __builtin_amdgcn_sched_barrier(0); } while (0)

// ---------------- merged weight convert+transpose (one launch for all 4) ----------------
// qkv 192x576=110592 | proj 192x192=36864 | fc1 192x768=147456 | fc2 768x192=147456
__global__ __launch_bounds__(256)
void convw_all_k(const float* __restrict__ qkv_w, const float* __restrict__ proj_w,
                 const float* __restrict__ fc1_w, const float* __restrict__ fc2_w,
                 __hip_bfloat16* __restrict__ wq, __hip_bfloat16* __restrict__ wp,
                 __hip_bfloat16* __restrict__ w1, __hip_bfloat16* __restrict__ w2)
{
    int idx = blockIdx.x * 256 + threadIdx.x;
    if (idx < 110592) {
        int k = idx / 576, n = idx - k * 576;
        wq[(size_t)n * 192 + k] = __float2bfloat16(qkv_w[idx]);
        return;
    }
    idx -= 110592;
    if (idx < 36864) {
        int k = idx / 192, n = idx - k * 192;
        wp[(size_t)n * 192 + k] = __float2bfloat16(proj_w[idx]);
        return;
    }
    idx -= 36864;
    if (idx < 147456) {
        int k = idx / 768, n = idx - k * 768;
        w1[(size_t)n * 192 + k] = __float2bfloat16(fc1_w[idx]);
        return;
    }
    idx -= 147456;
    if (idx < 147456) {
        int k = idx / 192, n = idx - k * 192;
        w2[(size_t)n * 768 + k] = __float2bfloat16(fc2_w[idx]);
    }
}

// ---------------- LN1 + shift + window-partition gather -> xw bf16 (window order) -------
__global__ __launch_bounds__(256)
void ln1_gather_k(const float* __restrict__ x, const float* __restrict__ g,
                  const float* __restrict__ bia, __hip_bfloat16* __restrict__ xw)
{
    const int wave = threadIdx.x >> 6, lane = threadIdx.x & 63;
    const int t = blockIdx.x * 4 + wave;        // window-ordered token, < 100352
    const int w = t / 49, n = t - w * 49;
    const int b = w >> 6, wrem = w & 63, wi = wrem >> 3, wj = wrem & 7;
    const int i = n / 7, j = n - i * 7;
    int sr = wi * 7 + i + 3; if (sr >= 56) sr -= 56;
    int sc = wj * 7 + j + 3; if (sc >= 56) sc -= 56;
    const float* xp = x + ((size_t)b * 3136 + sr * 56 + sc) * 192;
    float v0 = xp[lane], v1 = xp[lane + 64], v2 = xp[lane + 128];
    float s = v0 + v1 + v2;
    float q = v0 * v0 + v1 * v1 + v2 * v2;
    for (int off = 32; off > 0; off >>= 1) {
        s += __shfl_down(s, off, 64);
        q += __shfl_down(q, off, 64);
    }
    s = __shfl(s, 0, 64); q = __shfl(q, 0, 64);
    float mean = s * (1.0f / 192.0f);
    float var  = q * (1.0f / 192.0f) - mean * mean;
    float rstd = rsqrtf(var + 1e-5f);
    __hip_bfloat16* op = xw + (size_t)t * 192;
    op[lane]       = __float2bfloat16((v0 - mean) * rstd * g[lane]       + bia[lane]);
    op[lane + 64]  = __float2bfloat16((v1 - mean) * rstd * g[lane + 64]  + bia[lane + 64]);
    op[lane + 128] = __float2bfloat16((v2 - mean) * rstd * g[lane + 128] + bia[lane + 128]);
}

// ---------------- GEMM (QKV): 128x64 tile, global_load_lds staging ----------------
// 1-D grid, XCD-chunked swizzle (T1): the NOUT/64 col-blocks of one row-tile run
// temporally adjacent on ONE XCD -> the 128x192 A-tile stays L2-hot across its
// 9 re-reads. Requires gridDim.x % 8 == 0 (7056 = 882*8, bijective).
template<int K, int NOUT>
__global__ __launch_bounds__(256)
void gemm_qkv_k(const __hip_bfloat16* __restrict__ A,
                const __hip_bfloat16* __restrict__ Bt,
                const float* __restrict__ bias,
                __hip_bfloat16* __restrict__ outv)
{
    __shared__ __align__(16) __hip_bfloat16 As[128 * 32];   // 8 KB
    __shared__ __align__(16) __hip_bfloat16 Bs[64 * 32];    // 4 KB
    const int tid  = threadIdx.x;
    const int lane = tid & 63, wave = tid >> 6;
    const int quad = lane >> 4, l15 = lane & 15;

    const int nb = NOUT / 64;
    const int wk = (blockIdx.x & 7) * ((int)gridDim.x >> 3) + ((int)blockIdx.x >> 3);
    const int m0 = (wk / nb) * 128, n0 = (wk % nb) * 64;

    const int arow = lane >> 2, acol = (lane & 3) * 8;
    const __hip_bfloat16* Ag0 = A  + (size_t)(m0 + wave * 32 + arow)      * K + acol;
    const __hip_bfloat16* Ag1 = A  + (size_t)(m0 + wave * 32 + 16 + arow) * K + acol;
    const __hip_bfloat16* Bg  = Bt + (size_t)(n0 + wave * 16 + arow)      * K + acol;
    __hip_bfloat16* Al0 = &As[(wave * 32)      * 32];
    __hip_bfloat16* Al1 = &As[(wave * 32 + 16) * 32];
    __hip_bfloat16* Bl  = &Bs[(wave * 16)      * 32];

    fx4 acc[2][4];
#pragma unroll
    for (int mi = 0; mi < 2; mi++)
#pragma unroll
        for (int ni = 0; ni < 4; ni++) acc[mi][ni] = {0.f, 0.f, 0.f, 0.f};

    for (int k0 = 0; k0 < K; k0 += 32) {
        gload16(Ag0 + k0, Al0);
        gload16(Ag1 + k0, Al1);
        gload16(Bg  + k0, Bl);
        __syncthreads();
        bh8 a0 = *(const bh8*)&As[(wave * 32 + l15)      * 32 + quad * 8];
        bh8 a1 = *(const bh8*)&As[(wave * 32 + 16 + l15) * 32 + quad * 8];
        bh8 b0 = *(const bh8*)&Bs[(0 * 16 + l15) * 32 + quad * 8];
        bh8 b1 = *(const bh8*)&Bs[(1 * 16 + l15) * 32 + quad * 8];
        bh8 b2 = *(const bh8*)&Bs[(2 * 16 + l15) * 32 + quad * 8];
        bh8 b3 = *(const bh8*)&Bs[(3 * 16 + l15) * 32 + quad * 8];
        acc[0][0] = mfma_bf16(a0, b0, acc[0][0]);
        acc[0][1] = mfma_bf16(a0, b1, acc[0][1]);
        acc[0][2] = mfma_bf16(a0, b2, acc[0][2]);
        acc[0][3] = mfma_bf16(a0, b3, acc[0][3]);
        acc[1][0] = mfma_bf16(a1, b0, acc[1][0]);
        acc[1][1] = mfma_bf16(a1, b1, acc[1][1]);
        acc[1][2] = mfma_bf16(a1, b2, acc[1][2]);
        acc[1][3] = mfma_bf16(a1, b3, acc[1][3]);
        __syncthreads();
    }

#pragma unroll
    for (int mi = 0; mi < 2; mi++)
#pragma unroll
    for (int ni = 0; ni < 4; ni++) {
        const int n = n0 + ni * 16 + l15;
        const float bn = bias[n];
#pragma unroll
        for (int r = 0; r < 4; r++) {
            const int m = m0 + wave * 32 + mi * 16 + quad * 4 + r;
            float v = acc[mi][ni][r] + bn;
            if (n < 192) v *= 0.17677669529663687f;   // SCALE = 32^-0.5 on q
            outv[(size_t)m * NOUT + n] = __float2bfloat16(v);
        }
    }
}

// ---------------- fused MLP (R4-exact, best measured: 148 us) ----------------
// See R9 notes: register-capped at 2 waves/SIMD; 5 restructures all >= 148.
__global__ __launch_bounds__(256, 2)
void mlp_k(const __hip_bfloat16* __restrict__ A,      // y2 [100352][192] bf16
           const __hip_bfloat16* __restrict__ W1t,    // [768][192] bf16 (n-major)
           const __hip_bfloat16* __restrict__ W2t,    // [192][768] bf16 (n-major)
           const float* __restrict__ b1,
           const float* __restrict__ b2,
           float* __restrict__ out)                   // x1, in-place += mlp
{
    __shared__ __align__(16) __hip_bfloat16 W1s[2][6][32][32];  // 24 KB
    __shared__ __align__(16) __hip_bfloat16 W2s[2][192][32];    // 24 KB
    __shared__ __align__(16) __hip_bfloat16 Hs[128][40];        // 10 KB, 80B stride
    __shared__ __align__(16) float b1s[768];                    // 3 KB

    const int tid  = threadIdx.x;
    const int lane = tid & 63, wave = tid >> 6;
    const int quad = lane >> 4, l15 = lane & 15;
    const int m0 = blockIdx.x * 128;
    const int arow = lane >> 2, acol = (lane & 3) * 8;

    // b1 -> LDS once (192 threads x 16B). Drain ds_write before first barrier.
    if (tid < 192) ((fx4*)b1s)[tid] = ((const fx4*)b1)[tid];
    LGKM0;

    // X fragments in registers: 2 row-tiles x 6 k-chunks (48 VGPR).
    bh8 xr[2][6];
    const __hip_bfloat16* xg = A + (size_t)(m0 + wave * 32 + l15) * 192 + quad * 8;
#pragma unroll
    for (int rt = 0; rt < 2; rt++)
#pragma unroll
        for (int kc = 0; kc < 6; kc++)
            xr[rt][kc] = *(const bh8*)(xg + rt * 16 * 192 + kc * 32);

    // stage one 32-hidden chunk: W1 (32x192) + W2 (192x32), 6 gloads/wave.
    auto stage = [&](int bf, int c) {
#pragma unroll
        for (int i = 0; i < 3; i++) {
            const int g = wave * 3 + i;
            const int kc = g >> 1, half = g & 1;
            gload16(W1t + (size_t)(c * 32 + half * 16 + arow) * 192 + kc * 32 + acol,
                    &W1s[bf][kc][half * 16][0]);
            gload16(W2t + (size_t)(g * 16 + arow) * 768 + c * 32 + acol,
                    &W2s[bf][g * 16][0]);
        }
    };

    fx4 acc2[2][12];
#pragma unroll
    for (int rt = 0; rt < 2; rt++)
#pragma unroll
        for (int nt = 0; nt < 12; nt++) acc2[rt][nt] = {0.f, 0.f, 0.f, 0.f};

    stage(0, 0);
    stage(1, 1);

    int cur = 0;
    for (int c = 0; c < 23; ++c) {
        WAITV6;            // my chunk-c stage done; chunk-(c+1)'s 6 ops stay in flight
        BARR;              // all waves' chunk-c loads landed in buf[cur]

        // bias frags for this chunk (hidden-major: 4 consecutive h per reg)
        fx4 bv0 = *(const fx4*)&b1s[c * 32 + quad * 4];
        fx4 bv1 = *(const fx4*)&b1s[c * 32 + 16 + quad * 4];

        // ---- FC1 swapped: acc1[rt][ni] = H^T tile, K=192, X from registers ----
        fx4 acc1[2][2];
        acc1[0][0] = {0.f, 0.f, 0.f, 0.f}; acc1[0][1] = {0.f, 0.f, 0.f, 0.f};
        acc1[1][0] = {0.f, 0.f, 0.f, 0.f}; acc1[1][1] = {0.f, 0.f, 0.f, 0.f};
        __builtin_amdgcn_s_setprio(1);
#pragma unroll
        for (int kc = 0; kc < 6; kc++) {
#pragma unroll
            for (int ni = 0; ni < 2; ni++) {
                bh8 w = *(const bh8*)&W1s[cur][kc][ni * 16 + l15][quad * 8];
                acc1[0][ni] = mfma_bf16(w, xr[0][kc], acc1[0][ni]);
                acc1[1][ni] = mfma_bf16(w, xr[1][kc], acc1[1][ni]);
            }
        }
        __builtin_amdgcn_s_setprio(0);

        // ---- bias + gelu + pack -> Hs[m][h] (one b64 write per tile) ----
#pragma unroll
        for (int rt = 0; rt < 2; rt++) {
#pragma unroll
            for (int ni = 0; ni < 2; ni++) {
                const fx4 bv = ni ? bv1 : bv0;
                sh4 pk;
#pragma unroll
                for (int r = 0; r < 4; r++) {
                    float v = acc1[rt][ni][r] + bv[r];
                    float h = 0.5f * v * (1.0f + fast_erf(v * 0.70710678118654752f));
                    union { __hip_bfloat16 hb; short s; } u;
                    u.hb = __float2bfloat16(h);
                    pk[r] = u.s;
                }
                *(sh4*)&Hs[wave * 32 + rt * 16 + l15][ni * 16 + quad * 4] = pk;
            }
        }
        LGKM0;             // wave-private Hs write->read handoff (no vm drain)

        // ---- FC2: acc2 += H-chunk @ W2-chunk (K=32) ----
        bh8 ha0 = *(const bh8*)&Hs[wave * 32 + l15][quad * 8];
        bh8 ha1 = *(const bh8*)&Hs[wave * 32 + 16 + l15][quad * 8];
        __builtin_amdgcn_s_setprio(1);
#pragma unroll
        for (int nt = 0; nt < 12; nt++) {
            bh8 w2 = *(const bh8*)&W2s[cur][nt * 16 + l15][quad * 8];
            acc2[0][nt] = mfma_bf16(ha0, w2, acc2[0][nt]);
            acc2[1][nt] = mfma_bf16(ha1, w2, acc2[1][nt]);
        }
        __builtin_amdgcn_s_setprio(0);

        BARR;              // all waves done reading buf[cur]; safe to restage it
        if (c < 22) stage(cur, c + 2);
        cur ^= 1;
    }

    // ---- peeled chunk 23 (drain once) ----
    {
        WAITV0;
        BARR;
        fx4 bv0 = *(const fx4*)&b1s[23 * 32 + 0 * 16 + quad * 4];
        fx4 bv1 = *(const fx4*)&b1s[23 * 32 + 1 * 16 + quad * 4];
        fx4 acc1[2][2];
        acc1[0][0] = {0.f, 0.f, 0.f, 0.f}; acc1[0][1] = {0.f, 0.f, 0.f, 0.f};
        acc1[1][0] = {0.f, 0.f, 0.f, 0.f}; acc1[1][1] = {0.f, 0.f, 0.f, 0.f};
#pragma unroll
        for (int kc = 0; kc < 6; kc++) {
#pragma unroll
            for (int ni = 0; ni < 2; ni++) {
                bh8 w = *(const bh8*)&W1s[cur][kc][ni * 16 + l15][quad * 8];
                acc1[0][ni] = mfma_bf16(w, xr[0][kc], acc1[0][ni]);
                acc1[1][ni] = mfma_bf16(w, xr[1][kc], acc1[1][ni]);
            }
        }
#pragma unroll
        for (int rt = 0; rt < 2; rt++) {
#pragma unroll
            for (int ni = 0; ni < 2; ni++) {
                const fx4 bv = ni ? bv1 : bv0;
                sh4 pk;
#pragma unroll
                for (int r = 0; r < 4; r++) {
                    float v = acc1[rt][ni][r] + bv[r];
                    float h = 0.5f * v * (1.0f + fast_erf(v * 0.70710678118654752f));
                    union { __hip_bfloat16 hb; short s; } u;
                    u.hb = __float2bfloat16(h);
                    pk[r] = u.s;
                }
                *(sh4*)&Hs[wave * 32 + rt * 16 + l15][ni * 16 + quad * 4] = pk;
            }
        }
        LGKM0;
        bh8 ha0 = *(const bh8*)&Hs[wave * 32 + l15][quad * 8];
        bh8 ha1 = *(const bh8*)&Hs[wave * 32 + 16 + l15][quad * 8];
#pragma unroll
        for (int nt = 0; nt < 12; nt++) {
            bh8 w2 = *(const bh8*)&W2s[cur][nt * 16 + l15][quad * 8];
            acc2[0][nt] = mfma_bf16(ha0, w2, acc2[0][nt]);
            acc2[1][nt] = mfma_bf16(ha1, w2, acc2[1][nt]);
        }
    }

    // ---- epilogue: += b2 + residual (x1 already in out), fp32 in-place ----
#pragma unroll
    for (int rt = 0; rt < 2; rt++)
#pragma unroll
    for (int nt = 0; nt < 12; nt++) {
        const int n = nt * 16 + l15;
        const float bn = b2[n];
#pragma unroll
        for (int r = 0; r < 4; r++) {
            const int m = m0 + wave * 32 + rt * 16 + quad * 4 + r;
            out[(size_t)m * 192 + n] += acc2[rt][nt][r] + bn;
        }
    }
}

// ---------------- proj + residual + LN2 fused: tile 64 x 192 (full row) ----------------
// x1out = A*Wt + pb + xresid (fp32, -> d_out); y2out = LN(x1out)*g2+b2 (bf16)
__global__ __launch_bounds__(256)
void projln_k(const __hip_bfloat16* __restrict__ A,
              const __hip_bfloat16* __restrict__ Bt,
              const float* __restrict__ pb,
              const float* __restrict__ xresid,
              const float* __restrict__ g2,
              const float* __restrict__ b2,
              float* __restrict__ x1out,
              __hip_bfloat16* __restrict__ y2out)
{
    __shared__ __align__(16) __hip_bfloat16 As[64 * 32];    // 4 KB
    __shared__ __align__(16) __hip_bfloat16 Bs[192 * 32];   // 12 KB
    const int tid  = threadIdx.x;
    const int lane = tid & 63, wave = tid >> 6;
    const int quad = lane >> 4, l15 = lane & 15;
    const int m0 = blockIdx.x * 64;

    const int arow = lane >> 2, acol = (lane & 3) * 8;
    const __hip_bfloat16* Ag = A + (size_t)(m0 + wave * 16 + arow) * 192 + acol;
    __hip_bfloat16* Al = &As[(wave * 16) * 32];
    const __hip_bfloat16* Bg0 = Bt + (size_t)((wave + 0) * 16 + arow) * 192 + acol;
    const __hip_bfloat16* Bg1 = Bt + (size_t)((wave + 4) * 16 + arow) * 192 + acol;
    const __hip_bfloat16* Bg2 = Bt + (size_t)((wave + 8) * 16 + arow) * 192 + acol;
    __hip_bfloat16* Bl0 = &Bs[((wave + 0) * 16) * 32];
    __hip_bfloat16* Bl1 = &Bs[((wave + 4) * 16) * 32];
    __hip_bfloat16* Bl2 = &Bs[((wave + 8) * 16) * 32];

    fx4 acc[12];
#pragma unroll
    for (int ct = 0; ct < 12; ct++) acc[ct] = {0.f, 0.f, 0.f, 0.f};

    for (int k0 = 0; k0 < 192; k0 += 32) {
        gload16(Ag  + k0, Al);
        gload16(Bg0 + k0, Bl0);
        gload16(Bg1 + k0, Bl1);
        gload16(Bg2 + k0, Bl2);
        __syncthreads();
        bh8 a = *(const bh8*)&As[(wave * 16 + l15) * 32 + quad * 8];
#pragma unroll
        for (int ct = 0; ct < 12; ct++) {
            bh8 b = *(const bh8*)&Bs[(ct * 16 + l15) * 32 + quad * 8];
            acc[ct] = mfma_bf16(a, b, acc[ct]);
        }
        __syncthreads();
    }

#pragma unroll
    for (int r = 0; r < 4; r++) {
        const int row = m0 + wave * 16 + quad * 4 + r;
        float vv[12];
        float s = 0.f, q = 0.f;
#pragma unroll
        for (int ct = 0; ct < 12; ct++) {
            const int col = ct * 16 + l15;
            float v = acc[ct][r] + pb[col] + xresid[(size_t)row * 192 + col];
            vv[ct] = v;
            x1out[(size_t)row * 192 + col] = v;
            s += v;
            q += v * v;
        }
        s += __shfl_xor(s, 1, 64);  q += __shfl_xor(q, 1, 64);
        s += __shfl_xor(s, 2, 64);  q += __shfl_xor(q, 2, 64);
        s += __shfl_xor(s, 4, 64);  q += __shfl_xor(q, 4, 64);
        s += __shfl_xor(s, 8, 64);  q += __shfl_xor(q, 8, 64);
        float mean = s * (1.0f / 192.0f);
        float var  = q * (1.0f / 192.0f) - mean * mean;
        float rstd = rsqrtf(var + 1e-5f);
#pragma unroll
        for (int ct = 0; ct < 12; ct++) {
            const int col = ct * 16 + l15;
            float y = (vv[ct] - mean) * rstd * g2[col] + b2[col];
            y2out[(size_t)row * 192 + col] = __float2bfloat16(y);
        }
    }
}

// ---------------- attention: one block per (window, head) ----------------
// R10: (1) Vt stride 64 -> 72 elems (144B, 16B-aligned): V-scatter writes were
// 32-way bank conflicts (stride-128B, all lanes bank 0) and PV b128 reads were
// ~16-way (4 distinct start banks); stride-72 spreads start banks to ~8 -> 2-4
// way. (2) XCD-chunked block swizzle: the 6 head-blocks of one window now run
// on ONE XCD, so the 128B qkv lines shared by adjacent heads aren't re-fetched
// across XCDs (T1). 12288 % 8 == 0 -> bijective.
__global__ __launch_bounds__(256)
void attn_k(const __hip_bfloat16* __restrict__ qkv,   // [2048][49][576]
            const float* __restrict__ bias_table,
            __hip_bfloat16* __restrict__ aout)        // orig token order
{
    __shared__ __align__(16) __hip_bfloat16 Qb[64 * 32];
    __shared__ __align__(16) __hip_bfloat16 Kb[64 * 32];
    __shared__ __align__(16) __hip_bfloat16 Vt[32 * 72];   // Vt[d][m], stride 72
    __shared__ __align__(16) __hip_bfloat16 Ps[64 * 72];   // padded stride 72
    __shared__ float bias_h[169];

    const int tid  = threadIdx.x;
    const int lane = tid & 63, wave = tid >> 6;
    const int quad = lane >> 4, l15 = lane & 15;
    const int wk = (blockIdx.x & 7) * 1536 + ((int)blockIdx.x >> 3);
    const int w = wk / 6, hd = wk % 6;
    const int b = w >> 6, wrem = w & 63, wi = wrem >> 3, wj = wrem & 7;
    const size_t base = (size_t)w * 49 * 576 + hd * 32;

    if (tid < 169) bias_h[tid] = bias_table[tid * 6 + hd];

    bh8 z = {0, 0, 0, 0, 0, 0, 0, 0};
    {
        int row = tid >> 2, ch = (tid & 3) * 8;
        if (row < 49) {
            *(bh8*)&Qb[row * 32 + ch] = *(const bh8*)(qkv + base + (size_t)row * 576 + ch);
            *(bh8*)&Kb[row * 32 + ch] = *(const bh8*)(qkv + base + (size_t)row * 576 + 192 + ch);
        } else {
            *(bh8*)&Qb[row * 32 + ch] = z;
            *(bh8*)&Kb[row * 32 + ch] = z;
        }
        for (int i = tid; i < 288; i += 256)       // zero all of Vt (32*72/8 units)
            *(bh8*)&Vt[i * 8] = z;
    }
    __syncthreads();
    for (int idx = tid; idx < 49 * 32; idx += 256) {       // V transpose scatter
        int n = idx >> 5, d = idx & 31;
        Vt[d * 72 + n] = qkv[base + (size_t)n * 576 + 384 + d];
    }
    __syncthreads();

    // ---- scores S = Q K^T ----
    fx4 zf = {0.f, 0.f, 0.f, 0.f};
    bh8 aq = *(const bh8*)&Qb[(wave * 16 + l15) * 32 + quad * 8];
    fx4 sarr[4];
#pragma unroll
    for (int ni = 0; ni < 4; ni++) {
        bh8 bk = *(const bh8*)&Kb[(ni * 16 + l15) * 32 + quad * 8];
        sarr[ni] = mfma_bf16(aq, bk, zf);
    }

    // ---- bias + mask + softmax ----
    int iarr[4], ria[4], cia[4], mbi[4];
#pragma unroll
    for (int r = 0; r < 4; r++) {
        int i = wave * 16 + quad * 4 + r;
        int ri = i / 7, ci = i - ri * 7;
        iarr[r] = i; ria[r] = ri; cia[r] = ci;
        int ar = wi * 7 + ri, ac = wj * 7 + ci;
        int br = (ar < 49) ? 0 : ((ar < 53) ? 1 : 2);
        int bc = (ac < 49) ? 0 : ((ac < 53) ? 1 : 2);
        mbi[r] = br * 3 + bc;
    }
    float vals[4][4];   // [ni][r]
#pragma unroll
    for (int ni = 0; ni < 4; ni++) {
        int jcol = ni * 16 + l15;
        int rj = jcol / 7, cj = jcol - rj * 7;
        int ar = wi * 7 + rj, ac = wj * 7 + cj;
        int br = (ar < 49) ? 0 : ((ar < 53) ? 1 : 2);
        int bc = (ac < 49) ? 0 : ((ac < 53) ? 1 : 2);
        int mbj = br * 3 + bc;
#pragma unroll
        for (int r = 0; r < 4; r++) {
            float v;
            if (jcol >= 49)            v = -1e30f;
            else if (iarr[r] >= 49)    v = 0.0f;
            else {
                int bidx = (ria[r] - rj + 6) * 13 + (cia[r] - cj + 6);
                v = sarr[ni][r] + bias_h[bidx] + ((mbi[r] != mbj) ? -100.0f : 0.0f);
            }
            vals[ni][r] = v;
        }
    }
#pragma unroll
    for (int r = 0; r < 4; r++) {
        float mx = fmaxf(fmaxf(vals[0][r], vals[1][r]), fmaxf(vals[2][r], vals[3][r]));
        mx = fmaxf(mx, __shfl_xor(mx, 1, 64));
        mx = fmaxf(mx, __shfl_xor(mx, 2, 64));
        mx = fmaxf(mx, __shfl_xor(mx, 4, 64));
        mx = fmaxf(mx, __shfl_xor(mx, 8, 64));
        float e0 = __expf(vals[0][r] - mx);
        float e1 = __expf(vals[1][r] - mx);
        float e2 = __expf(vals[2][r] - mx);
        float e3 = __expf(vals[3][r] - mx);
        float sm = e0 + e1 + e2 + e3;
        sm += __shfl_xor(sm, 1, 64);
        sm += __shfl_xor(sm, 2, 64);
        sm += __shfl_xor(sm, 4, 64);
        sm += __shfl_xor(sm, 8, 64);
        float inv = 1.0f / sm;
        int prow = (wave * 16 + quad * 4 + r) * 72;
        Ps[prow + 0 * 16 + l15] = __float2bfloat16(e0 * inv);
        Ps[prow + 1 * 16 + l15] = __float2bfloat16(e1 * inv);
        Ps[prow + 2 * 16 + l15] = __float2bfloat16(e2 * inv);
        Ps[prow + 3 * 16 + l15] = __float2bfloat16(e3 * inv);
    }
    __syncthreads();

    // ---- O = P V ----
    fx4 o0 = zf, o1 = zf;
#pragma unroll
    for (int k0 = 0; k0 < 64; k0 += 32) {
        bh8 ap  = *(const bh8*)&Ps[(wave * 16 + l15) * 72 + k0 + quad * 8];
        bh8 bv0 = *(const bh8*)&Vt[(l15)      * 72 + k0 + quad * 8];
        bh8 bv1 = *(const bh8*)&Vt[(16 + l15) * 72 + k0 + quad * 8];
        o0 = mfma_bf16(ap, bv0, o0);
        o1 = mfma_bf16(ap, bv1, o1);
    }

    // ---- write out in ORIGINAL token order ----
#pragma unroll
    for (int r = 0; r < 4; r++) {
        int m = wave * 16 + quad * 4 + r;
        if (m < 49) {
            int i = m / 7, j2 = m - i * 7;
            int orow = wi * 7 + i + 3;  if (orow >= 56) orow -= 56;
            int ocol = wj * 7 + j2 + 3; if (ocol >= 56) ocol -= 56;
            size_t t = (size_t)b * 3136 + orow * 56 + ocol;
            aout[t * 192 + hd * 32 + l15]      = __float2bfloat16(o0[r]);
            aout[t * 192 + hd * 32 + 16 + l15] = __float2bfloat16(o1[r]);
        }
    }
}

// ---------------- launch ----------------
// Layout (peak 193.6 MB):
//   buf1 @ 0          38,535,168 B : xw (window order) -> attn_out (orig order) -> y2
//   buf2 @ 38,535,168 154,140,672 B: qkv full (115.6 MB)
//   weights @ 192,675,840 .. 193,560,576
//   x1 lives in d_out (fp32); mlp_k does in-place owner-computes residual add on d_out.
extern "C" void kernel_launch(void* const* d_in, const int* in_sizes, int n_in,
                              void* d_out, int out_size, void* d_ws, size_t ws_size,
                              hipStream_t stream)
{
    const float* x      = (const float*)d_in[0];
    const float* n1g    = (const float*)d_in[1];
    const float* n1b    = (const float*)d_in[2];
    const float* qkv_w  = (const float*)d_in[3];
    const float* qkv_b  = (const float*)d_in[4];
    const float* proj_w = (const float*)d_in[5];
    const float* proj_b = (const float*)d_in[6];
    const float* btab   = (const float*)d_in[7];
    const float* n2g    = (const float*)d_in[8];
    const float* n2b    = (const float*)d_in[9];
    const float* fc1_w  = (const float*)d_in[10];
    const float* fc1_b  = (const float*)d_in[11];
    const float* fc2_w  = (const float*)d_in[12];
    const float* fc2_b  = (const float*)d_in[13];

    char* ws = (char*)d_ws;
    __hip_bfloat16* buf1    = (__hip_bfloat16*)(ws + 0);           // 38,535,168 B
    __hip_bfloat16* buf2    = (__hip_bfloat16*)(ws + 38535168);    // 154,140,672 B
    __hip_bfloat16* wt_qkv  = (__hip_bfloat16*)(ws + 192675840);   // 221,184 B
    __hip_bfloat16* wt_proj = (__hip_bfloat16*)(ws + 192897024);   // 73,728 B
    __hip_bfloat16* wt_fc1  = (__hip_bfloat16*)(ws + 192970752);   // 294,912 B
    __hip_bfloat16* wt_fc2  = (__hip_bfloat16*)(ws + 193265664);   // 294,912 B
    float*          x1      = (float*)d_out;                       // 77,070,336 B

    // all 4 weight converts in one launch (442368 elems)
    convw_all_k<<<dim3(1728), 256, 0, stream>>>(qkv_w, proj_w, fc1_w, fc2_w,
                                                wt_qkv, wt_proj, wt_fc1, wt_fc2);

    // LN1 + shift + window partition: 100352 tokens -> buf1 (bf16, window order)
    ln1_gather_k<<<dim3(25088), 256, 0, stream>>>(x, n1g, n1b, buf1);

    // QKV: [100352 x 192] x [576 x 192]^T -> buf2 (bf16), XCD-chunked swizzle
    gemm_qkv_k<192, 576><<<dim3(7056), 256, 0, stream>>>(buf1, wt_qkv, qkv_b, buf2);

    // attention: 2048 windows x 6 heads -> buf1 (bf16, orig token order)
    attn_k<<<dim3(12288), 256, 0, stream>>>(buf2, btab, buf1);

    // proj + residual + LN2: x1 -> d_out (fp32), y2 -> buf1 (bf16, in-place over attn_out)
    projln_k<<<dim3(1568), 256, 0, stream>>>(buf1, wt_proj, proj_b, x, n2g, n2b, x1, buf1);

    // fused FC1 + gelu + FC2 + residual (in-place on d_out), 128 rows/block
    mlp_k<<<dim3(784), 256, 0, stream>>>(buf1, wt_fc1, wt_fc2, fc1_b, fc2_b, x1);
}